// Round 5
// baseline (159.143 us; speedup 1.0000x reference)
//
#include <hip/hip_runtime.h>

constexpr int NB = 4;
constexpr int CC = 128;
constexpr int HH = 64;
constexpr int WW = 64;
constexpr int HWp = HH * WW;      // 4096
constexpr int NHEADS = 4;
constexpr int K2 = 25;

typedef unsigned int   uint32;
typedef unsigned short ushort16;
typedef __attribute__((ext_vector_type(8))) short bf16x8;
typedef __attribute__((ext_vector_type(4))) float f32x4;

__device__ __forceinline__ ushort16 f2bf(float x) {
    uint32 b = __float_as_uint(x);
    return (ushort16)((b + 0x7FFFu + ((b >> 16) & 1u)) >> 16);   // RNE
}
__device__ __forceinline__ uint32 pack2(float lo, float hi) {
    return ((uint32)f2bf(hi) << 16) | (uint32)f2bf(lo);
}
__device__ __forceinline__ float bf_lo(uint32 u) { return __uint_as_float(u << 16); }
__device__ __forceinline__ float bf_hi(uint32 u) { return __uint_as_float(u & 0xFFFF0000u); }

// ---------------------------------------------------------------------------
// Kernel 0: convert Wq/Wk/Wv/Wfc fp32 -> bf16 (row-major preserved).
// ---------------------------------------------------------------------------
__global__ __launch_bounds__(256) void wconv_kernel(
    const float* __restrict__ Wq, const float* __restrict__ Wk,
    const float* __restrict__ Wv, const float* __restrict__ Wfc,
    ushort16* __restrict__ wbf)
{
    int i = blockIdx.x * 256 + threadIdx.x;   // 0..16383
    int m = i >> 12;
    int j = i & 4095;
    const float* s = (m == 0) ? Wq : ((m == 1) ? Wk : ((m == 2) ? Wv : Wfc));
    float4 f = reinterpret_cast<const float4*>(s)[j];
    uint32 w0 = pack2(f.x, f.y);
    uint32 w1 = pack2(f.z, f.w);
    uint32* d = reinterpret_cast<uint32*>(wbf + (size_t)m * 16384);
    d[j * 2]     = w0;
    d[j * 2 + 1] = w1;
}

// ---------------------------------------------------------------------------
// Kernel 1: MFMA projections. C[out=128][pix] = W[128x128] * X[c=128][pix].
// grid = 3 * NB * 64 = 768 blocks, 256 threads (2x2 wave grid).
// ---------------------------------------------------------------------------
__global__ __launch_bounds__(256) void proj_mfma(
    const float* __restrict__ q, const float* __restrict__ k, const float* __restrict__ v,
    const ushort16* __restrict__ wbf,
    ushort16* __restrict__ qp, ushort16* __restrict__ kp, ushort16* __restrict__ vp)
{
    __shared__ __align__(16) ushort16 lx[64 * 132];

    int blk = blockIdx.x;
    int p   = blk >> 8;
    int rem = blk & 255;
    int n   = rem >> 6;
    int pt  = rem & 63;
    int pix0 = pt * 64;

    const float*    X  = (p == 0) ? q  : ((p == 1) ? k  : v);
    ushort16*       O  = (p == 0) ? qp : ((p == 1) ? kp : vp);
    const ushort16* Wb = wbf + (size_t)p * 16384;
    const float*    Xb = X + (size_t)n * CC * HWp + pix0;

    int lane = threadIdx.x & 63;
    int cg   = threadIdx.x >> 6;

#pragma unroll
    for (int i = 0; i < 16; ++i) {
        int c0 = i * 8 + cg * 2;
        float a = Xb[c0 * HWp + lane];
        float b = Xb[(c0 + 1) * HWp + lane];
        *reinterpret_cast<uint32*>(&lx[lane * 132 + c0]) = pack2(a, b);
    }
    __syncthreads();

    int wid = threadIdx.x >> 6;
    int wr  = wid >> 1, wc = wid & 1;
    int p16 = lane & 15, kg = lane >> 4;

    f32x4 acc[4][2] = {};

#pragma unroll
    for (int k0 = 0; k0 < 128; k0 += 32) {
        bf16x8 A[4], B[2];
#pragma unroll
        for (int ai = 0; ai < 4; ++ai) {
            int o = wr * 64 + ai * 16 + p16;
            A[ai] = *reinterpret_cast<const bf16x8*>(&Wb[o * 128 + k0 + kg * 8]);
        }
#pragma unroll
        for (int bj = 0; bj < 2; ++bj) {
            int px = wc * 32 + bj * 16 + p16;
            const ushort16* sp = &lx[px * 132 + k0 + kg * 8];
            struct { unsigned long long lo, hi; } t;
            t.lo = *reinterpret_cast<const unsigned long long*>(sp);
            t.hi = *reinterpret_cast<const unsigned long long*>(sp + 4);
            B[bj] = __builtin_bit_cast(bf16x8, t);
        }
#pragma unroll
        for (int ai = 0; ai < 4; ++ai)
#pragma unroll
            for (int bj = 0; bj < 2; ++bj)
                acc[ai][bj] = __builtin_amdgcn_mfma_f32_16x16x32_bf16(
                    A[ai], B[bj], acc[ai][bj], 0, 0, 0);
    }

    ushort16* Ob = O + (size_t)(n * HWp + pix0) * CC;
#pragma unroll
    for (int ai = 0; ai < 4; ++ai) {
        int ob = wr * 64 + ai * 16 + kg * 4;
#pragma unroll
        for (int bj = 0; bj < 2; ++bj) {
            int px = wc * 32 + bj * 16 + p16;
            uint32* dst = reinterpret_cast<uint32*>(&Ob[(size_t)px * CC + ob]);
            dst[0] = pack2(acc[ai][bj][0], acc[ai][bj][1]);
            dst[1] = pack2(acc[ai][bj][2], acc[ai][bj][3]);
        }
    }
}

// ---------------------------------------------------------------------------
// Kernel 2a: QK phase. 16 lanes/pixel (8 ch/lane), 16 pixels per 256-thr block.
// Reads q from qp slab; writes attn (fp32) + bf16 l-record IN-PLACE over q.
// Record layout per pixel (256B): head h occupies bytes [h*64,(h+1)*64),
// words 0..12 = l[0..24] bf16-pairs; lane (4h+j) writes words 4j..4j+3.
// ---------------------------------------------------------------------------
__global__ __launch_bounds__(256, 4) void attn_qk(
    ushort16* qrec,
    const ushort16* __restrict__ kp,
    const float* __restrict__ flow,
    float* __restrict__ attn)
{
    int blk = blockIdx.x;                        // 0..1023
    int swz = ((blk & 7) << 7) + (blk >> 3);     // XCD-contiguous bands
    int tid = threadIdx.x;
    int pix = swz * 16 + (tid >> 4);
    int lg  = tid & 15;
    int c0  = lg * 8;
    int n   = pix >> 12;
    int yx  = pix & 4095;
    int y   = yx >> 6, x = yx & 63;

    float fx = flow[((size_t)n * 2 + 0) * HWp + yx];
    float fy = flow[((size_t)n * 2 + 1) * HWp + yx];
    float pxf = (float)x + fx, pyf = (float)y + fy;
    float X0 = floorf(pxf), Y0 = floorf(pyf);
    float wx = pxf - X0,    wy = pyf - Y0;
    int ix0 = (int)X0 - 2,  iy0 = (int)Y0 - 2;

    int coff[6], roff[6];
    float mx[6], my[6];
#pragma unroll
    for (int r = 0; r < 6; ++r) {
        int xi = ix0 + r;
        mx[r] = (xi >= 0 && xi < WW) ? 1.f : 0.f;
        int xc = xi < 0 ? 0 : (xi > WW - 1 ? WW - 1 : xi);
        coff[r] = xc * CC;
        int yi = iy0 + r;
        my[r] = (yi >= 0 && yi < HH) ? 1.f : 0.f;
        int yc = yi < 0 ? 0 : (yi > HH - 1 ? HH - 1 : yi);
        roff[r] = yc * (WW * CC);
    }
    float wl[5], wr_[5], vt[5], vb2[5];
#pragma unroll
    for (int i = 0; i < 5; ++i) {
        wl[i]  = (1.f - wx) * mx[i];
        wr_[i] = wx * mx[i + 1];
        vt[i]  = (1.f - wy) * my[i];
        vb2[i] = wy * my[i + 1];
    }

    ushort16* qb = qrec + (size_t)pix * CC + c0;
    uint4 qraw = *reinterpret_cast<const uint4*>(qb);
    float qv[8] = { bf_lo(qraw.x), bf_hi(qraw.x), bf_lo(qraw.y), bf_hi(qraw.y),
                    bf_lo(qraw.z), bf_hi(qraw.z), bf_lo(qraw.w), bf_hi(qraw.w) };

    const ushort16* kb = kp + (size_t)n * HWp * CC + c0;

    float l[25];
#pragma unroll
    for (int r = 0; r < 6; ++r) {
        const ushort16* krow = kb + roff[r];
        float pd[6];
#pragma unroll
        for (int rx = 0; rx < 6; ++rx) {
            uint4 u = *reinterpret_cast<const uint4*>(krow + coff[rx]);
            float s = qv[0] * bf_lo(u.x) + qv[1] * bf_hi(u.x);
            s = fmaf(qv[2], bf_lo(u.y), s);
            s = fmaf(qv[3], bf_hi(u.y), s);
            s = fmaf(qv[4], bf_lo(u.z), s);
            s = fmaf(qv[5], bf_hi(u.z), s);
            s = fmaf(qv[6], bf_lo(u.w), s);
            s = fmaf(qv[7], bf_hi(u.w), s);
            pd[rx] = s;
        }
        float hbr[5];
#pragma unroll
        for (int kx = 0; kx < 5; ++kx)
            hbr[kx] = pd[kx] * wl[kx] + pd[kx + 1] * wr_[kx];
        if (r < 5) {
#pragma unroll
            for (int kx = 0; kx < 5; ++kx) l[r * 5 + kx] = hbr[kx] * vt[r];
        }
        if (r >= 1) {
#pragma unroll
            for (int kx = 0; kx < 5; ++kx)
                l[(r - 1) * 5 + kx] = fmaf(hbr[kx], vb2[r - 1], l[(r - 1) * 5 + kx]);
        }
    }

#pragma unroll
    for (int kk = 0; kk < 25; ++kk) {
        float s = l[kk];
        s += __shfl_xor(s, 1);
        s += __shfl_xor(s, 2);
        l[kk] = s * 0.17677669529663687f;   // 1/sqrt(32)
    }

    float m = l[0];
#pragma unroll
    for (int kk = 1; kk < 25; ++kk) m = fmaxf(m, l[kk]);
    float sum = 0.f;
#pragma unroll
    for (int kk = 0; kk < 25; ++kk) { l[kk] = __expf(l[kk] - m); sum += l[kk]; }
    float inv = 1.f / sum;
#pragma unroll
    for (int kk = 0; kk < 25; ++kk) l[kk] *= inv;

    // attn write (fp32, reference layout)
    {
        int head = lg >> 2, j = lg & 3;
        float* ab = attn + (((size_t)n * NHEADS + head) * K2) * HWp + yx;
#pragma unroll
        for (int kk = 0; kk < 25; ++kk)
            if ((kk & 3) == j) ab[(size_t)kk * HWp] = l[kk];
    }

    // bf16 l-record, in-place over the q values this lane consumed
    {
        int j = lg & 3;
        uint4 rec;
        if (j == 0)
            rec = make_uint4(pack2(l[0], l[1]),  pack2(l[2], l[3]),
                             pack2(l[4], l[5]),  pack2(l[6], l[7]));
        else if (j == 1)
            rec = make_uint4(pack2(l[8], l[9]),  pack2(l[10], l[11]),
                             pack2(l[12], l[13]), pack2(l[14], l[15]));
        else if (j == 2)
            rec = make_uint4(pack2(l[16], l[17]), pack2(l[18], l[19]),
                             pack2(l[20], l[21]), pack2(l[22], l[23]));
        else
            rec = make_uint4(pack2(l[24], 0.f), 0u, 0u, 0u);
        *reinterpret_cast<uint4*>(qb) = rec;
    }
}

// ---------------------------------------------------------------------------
// Kernel 2b: PV phase. Reads l-record (broadcast within head group) + flow,
// gathers V, writes oh IN-PLACE over the record (reads precede writes in
// wave program order; each pixel owned by one wave).
// ---------------------------------------------------------------------------
__global__ __launch_bounds__(256, 4) void attn_pv(
    ushort16* rec_oh,
    const ushort16* __restrict__ vp,
    const float* __restrict__ flow)
{
    int blk = blockIdx.x;
    int swz = ((blk & 7) << 7) + (blk >> 3);
    int tid = threadIdx.x;
    int pix = swz * 16 + (tid >> 4);
    int lg  = tid & 15;
    int c0  = lg * 8;
    int n   = pix >> 12;
    int yx  = pix & 4095;
    int y   = yx >> 6, x = yx & 63;
    int head = lg >> 2;

    // record load (4x uint4, broadcast across the 4 lanes of the head)
    const uint4* rb = reinterpret_cast<const uint4*>(
        rec_oh + (size_t)pix * CC + head * 32);
    uint4 u0 = rb[0], u1 = rb[1], u2 = rb[2], u3 = rb[3];
    float l[25];
    l[0]  = bf_lo(u0.x); l[1]  = bf_hi(u0.x);
    l[2]  = bf_lo(u0.y); l[3]  = bf_hi(u0.y);
    l[4]  = bf_lo(u0.z); l[5]  = bf_hi(u0.z);
    l[6]  = bf_lo(u0.w); l[7]  = bf_hi(u0.w);
    l[8]  = bf_lo(u1.x); l[9]  = bf_hi(u1.x);
    l[10] = bf_lo(u1.y); l[11] = bf_hi(u1.y);
    l[12] = bf_lo(u1.z); l[13] = bf_hi(u1.z);
    l[14] = bf_lo(u1.w); l[15] = bf_hi(u1.w);
    l[16] = bf_lo(u2.x); l[17] = bf_hi(u2.x);
    l[18] = bf_lo(u2.y); l[19] = bf_hi(u2.y);
    l[20] = bf_lo(u2.z); l[21] = bf_hi(u2.z);
    l[22] = bf_lo(u2.w); l[23] = bf_hi(u2.w);
    l[24] = bf_lo(u3.x);

    float fx = flow[((size_t)n * 2 + 0) * HWp + yx];
    float fy = flow[((size_t)n * 2 + 1) * HWp + yx];
    float pxf = (float)x + fx, pyf = (float)y + fy;
    float X0 = floorf(pxf), Y0 = floorf(pyf);
    float wx = pxf - X0,    wy = pyf - Y0;
    int ix0 = (int)X0 - 2,  iy0 = (int)Y0 - 2;

    int coff[6], roff[6];
    float mx[6], my[6];
#pragma unroll
    for (int r = 0; r < 6; ++r) {
        int xi = ix0 + r;
        mx[r] = (xi >= 0 && xi < WW) ? 1.f : 0.f;
        int xc = xi < 0 ? 0 : (xi > WW - 1 ? WW - 1 : xi);
        coff[r] = xc * CC;
        int yi = iy0 + r;
        my[r] = (yi >= 0 && yi < HH) ? 1.f : 0.f;
        int yc = yi < 0 ? 0 : (yi > HH - 1 ? HH - 1 : yi);
        roff[r] = yc * (WW * CC);
    }

    const ushort16* vbp = vp + (size_t)n * HWp * CC + c0;

    float acc[8] = {0.f, 0.f, 0.f, 0.f, 0.f, 0.f, 0.f, 0.f};
    float lhp[6] = {0.f, 0.f, 0.f, 0.f, 0.f, 0.f};
#pragma unroll
    for (int ry = 0; ry < 6; ++ry) {
        float lhc[6];
        if (ry < 5) {
            lhc[0] = l[ry * 5 + 0] * (1.f - wx);
#pragma unroll
            for (int rx = 1; rx < 5; ++rx)
                lhc[rx] = l[ry * 5 + rx] * (1.f - wx) + l[ry * 5 + rx - 1] * wx;
            lhc[5] = l[ry * 5 + 4] * wx;
        } else {
#pragma unroll
            for (int rx = 0; rx < 6; ++rx) lhc[rx] = 0.f;
        }
        float wyc = (1.f - wy) * my[ry];
        float wyp = wy * my[ry];
        const ushort16* vrow = vbp + roff[ry];
#pragma unroll
        for (int rx = 0; rx < 6; ++rx) {
            float w6 = (lhc[rx] * wyc + lhp[rx] * wyp) * mx[rx];
            uint4 u = *reinterpret_cast<const uint4*>(vrow + coff[rx]);
            acc[0] = fmaf(bf_lo(u.x), w6, acc[0]);
            acc[1] = fmaf(bf_hi(u.x), w6, acc[1]);
            acc[2] = fmaf(bf_lo(u.y), w6, acc[2]);
            acc[3] = fmaf(bf_hi(u.y), w6, acc[3]);
            acc[4] = fmaf(bf_lo(u.z), w6, acc[4]);
            acc[5] = fmaf(bf_hi(u.z), w6, acc[5]);
            acc[6] = fmaf(bf_lo(u.w), w6, acc[6]);
            acc[7] = fmaf(bf_hi(u.w), w6, acc[7]);
        }
#pragma unroll
        for (int rx = 0; rx < 6; ++rx) lhp[rx] = lhc[rx];
    }

    uint4 o;
    o.x = pack2(acc[0], acc[1]);
    o.y = pack2(acc[2], acc[3]);
    o.z = pack2(acc[4], acc[5]);
    o.w = pack2(acc[6], acc[7]);
    *reinterpret_cast<uint4*>(rec_oh + (size_t)pix * CC + c0) = o;   // oh
}

// ---------------------------------------------------------------------------
// Kernel 3: MFMA final projection. out[o][pix] = Wfc * oh[pix][c]^T.
// ---------------------------------------------------------------------------
__global__ __launch_bounds__(256) void fc_mfma(
    const ushort16* __restrict__ oh, const ushort16* __restrict__ wfcb,
    float* __restrict__ out)
{
    int blk = blockIdx.x;
    int gp0 = blk * 64;
    int n   = gp0 >> 12;
    int yx0 = gp0 & 4095;

    int lane = threadIdx.x & 63;
    int wid  = threadIdx.x >> 6;
    int wr = wid >> 1, wc = wid & 1;
    int p16 = lane & 15, kg = lane >> 4;

    const ushort16* ohb = oh + (size_t)gp0 * CC;

    f32x4 acc[4][2] = {};

#pragma unroll
    for (int k0 = 0; k0 < 128; k0 += 32) {
        bf16x8 A[4], B[2];
#pragma unroll
        for (int ai = 0; ai < 4; ++ai) {
            int o = wr * 64 + ai * 16 + p16;
            A[ai] = *reinterpret_cast<const bf16x8*>(&wfcb[o * 128 + k0 + kg * 8]);
        }
#pragma unroll
        for (int bj = 0; bj < 2; ++bj) {
            int px = wc * 32 + bj * 16 + p16;
            B[bj] = *reinterpret_cast<const bf16x8*>(&ohb[(size_t)px * CC + k0 + kg * 8]);
        }
#pragma unroll
        for (int ai = 0; ai < 4; ++ai)
#pragma unroll
            for (int bj = 0; bj < 2; ++bj)
                acc[ai][bj] = __builtin_amdgcn_mfma_f32_16x16x32_bf16(
                    A[ai], B[bj], acc[ai][bj], 0, 0, 0);
    }

    float* ob = out + (size_t)n * CC * HWp + yx0;
#pragma unroll
    for (int ai = 0; ai < 4; ++ai) {
        int o = wr * 64 + ai * 16 + kg * 4;
#pragma unroll
        for (int bj = 0; bj < 2; ++bj) {
            int px = wc * 32 + bj * 16 + p16;
#pragma unroll
            for (int r = 0; r < 4; ++r)
                ob[(size_t)(o + r) * HWp + px] = acc[ai][bj][r];
        }
    }
}

// ---------------------------------------------------------------------------
extern "C" void kernel_launch(void* const* d_in, const int* in_sizes, int n_in,
                              void* d_out, int out_size, void* d_ws, size_t ws_size,
                              hipStream_t stream)
{
    const float* q    = (const float*)d_in[0];
    const float* k    = (const float*)d_in[1];
    const float* v    = (const float*)d_in[2];
    const float* flow = (const float*)d_in[3];
    const float* Wq   = (const float*)d_in[4];
    const float* Wk   = (const float*)d_in[5];
    const float* Wv   = (const float*)d_in[6];
    const float* Wfc  = (const float*)d_in[7];

    float* out  = (float*)d_out;                          // [N][C][H][W]
    float* attn = out + (size_t)NB * CC * HWp;            // [N][NHEADS][K2][H][W]

    ushort16* ws = (ushort16*)d_ws;
    size_t slab = (size_t)NB * HWp * CC;
    ushort16* qp  = ws;                                   // q -> l-records -> oh
    ushort16* kp  = ws + slab;
    ushort16* vp  = ws + 2 * slab;
    ushort16* wbf = ws + 3 * slab;

    wconv_kernel<<<dim3(64), dim3(256), 0, stream>>>(Wq, Wk, Wv, Wfc, wbf);
    proj_mfma<<<dim3(768), dim3(256), 0, stream>>>(q, k, v, wbf, qp, kp, vp);
    attn_qk<<<dim3(1024), dim3(256), 0, stream>>>(qp, kp, flow, attn);
    attn_pv<<<dim3(1024), dim3(256), 0, stream>>>(qp, vp, flow);
    fc_mfma<<<dim3(256), dim3(256), 0, stream>>>(qp, wbf + 3 * 16384, out);
}

// Round 6
// 50.739 us; speedup vs baseline: 3.1365x; 3.1365x over previous
//
#include <hip/hip_runtime.h>

constexpr int NB = 4;
constexpr int CC = 128;
constexpr int HH = 64;
constexpr int WW = 64;
constexpr int HWp = HH * WW;      // 4096
constexpr int NHEADS = 4;
constexpr int K2 = 25;

typedef unsigned int   uint32;
typedef unsigned short ushort16;
typedef __attribute__((ext_vector_type(8))) short bf16x8;
typedef __attribute__((ext_vector_type(4))) float f32x4;

__device__ __forceinline__ ushort16 f2bf(float x) {
    uint32 b = __float_as_uint(x);
    return (ushort16)((b + 0x7FFFu + ((b >> 16) & 1u)) >> 16);   // RNE
}
__device__ __forceinline__ uint32 pack2(float lo, float hi) {
    return ((uint32)f2bf(hi) << 16) | (uint32)f2bf(lo);
}
__device__ __forceinline__ float bf_lo(uint32 u) { return __uint_as_float(u << 16); }
__device__ __forceinline__ float bf_hi(uint32 u) { return __uint_as_float(u & 0xFFFF0000u); }

// ---------------------------------------------------------------------------
// Kernel 0: convert Wq/Wk/Wv/Wfc fp32 -> bf16 (row-major preserved).
// ---------------------------------------------------------------------------
__global__ __launch_bounds__(256) void wconv_kernel(
    const float* __restrict__ Wq, const float* __restrict__ Wk,
    const float* __restrict__ Wv, const float* __restrict__ Wfc,
    ushort16* __restrict__ wbf)
{
    int i = blockIdx.x * 256 + threadIdx.x;   // 0..16383
    int m = i >> 12;
    int j = i & 4095;
    const float* s = (m == 0) ? Wq : ((m == 1) ? Wk : ((m == 2) ? Wv : Wfc));
    float4 f = reinterpret_cast<const float4*>(s)[j];
    uint32 w0 = pack2(f.x, f.y);
    uint32 w1 = pack2(f.z, f.w);
    uint32* d = reinterpret_cast<uint32*>(wbf + (size_t)m * 16384);
    d[j * 2]     = w0;
    d[j * 2 + 1] = w1;
}

// ---------------------------------------------------------------------------
// Kernel 1: MFMA projections. C[out=128][pix] = W[128x128] * X[c=128][pix].
// grid = 3 * NB * 64 = 768 blocks, 256 threads (2x2 wave grid).
// ---------------------------------------------------------------------------
__global__ __launch_bounds__(256) void proj_mfma(
    const float* __restrict__ q, const float* __restrict__ k, const float* __restrict__ v,
    const ushort16* __restrict__ wbf,
    ushort16* __restrict__ qp, ushort16* __restrict__ kp, ushort16* __restrict__ vp)
{
    __shared__ __align__(16) ushort16 lx[64 * 132];

    int blk = blockIdx.x;
    int p   = blk >> 8;
    int rem = blk & 255;
    int n   = rem >> 6;
    int pt  = rem & 63;
    int pix0 = pt * 64;

    const float*    X  = (p == 0) ? q  : ((p == 1) ? k  : v);
    ushort16*       O  = (p == 0) ? qp : ((p == 1) ? kp : vp);
    const ushort16* Wb = wbf + (size_t)p * 16384;
    const float*    Xb = X + (size_t)n * CC * HWp + pix0;

    int lane = threadIdx.x & 63;
    int cg   = threadIdx.x >> 6;

#pragma unroll
    for (int i = 0; i < 16; ++i) {
        int c0 = i * 8 + cg * 2;
        float a = Xb[c0 * HWp + lane];
        float b = Xb[(c0 + 1) * HWp + lane];
        *reinterpret_cast<uint32*>(&lx[lane * 132 + c0]) = pack2(a, b);
    }
    __syncthreads();

    int wid = threadIdx.x >> 6;
    int wr  = wid >> 1, wc = wid & 1;
    int p16 = lane & 15, kg = lane >> 4;

    f32x4 acc[4][2] = {};

#pragma unroll
    for (int k0 = 0; k0 < 128; k0 += 32) {
        bf16x8 A[4], B[2];
#pragma unroll
        for (int ai = 0; ai < 4; ++ai) {
            int o = wr * 64 + ai * 16 + p16;
            A[ai] = *reinterpret_cast<const bf16x8*>(&Wb[o * 128 + k0 + kg * 8]);
        }
#pragma unroll
        for (int bj = 0; bj < 2; ++bj) {
            int px = wc * 32 + bj * 16 + p16;
            const ushort16* sp = &lx[px * 132 + k0 + kg * 8];
            struct { unsigned long long lo, hi; } t;
            t.lo = *reinterpret_cast<const unsigned long long*>(sp);
            t.hi = *reinterpret_cast<const unsigned long long*>(sp + 4);
            B[bj] = __builtin_bit_cast(bf16x8, t);
        }
#pragma unroll
        for (int ai = 0; ai < 4; ++ai)
#pragma unroll
            for (int bj = 0; bj < 2; ++bj)
                acc[ai][bj] = __builtin_amdgcn_mfma_f32_16x16x32_bf16(
                    A[ai], B[bj], acc[ai][bj], 0, 0, 0);
    }

    ushort16* Ob = O + (size_t)(n * HWp + pix0) * CC;
#pragma unroll
    for (int ai = 0; ai < 4; ++ai) {
        int ob = wr * 64 + ai * 16 + kg * 4;
#pragma unroll
        for (int bj = 0; bj < 2; ++bj) {
            int px = wc * 32 + bj * 16 + p16;
            uint32* dst = reinterpret_cast<uint32*>(&Ob[(size_t)px * CC + ob]);
            dst[0] = pack2(acc[ai][bj][0], acc[ai][bj][1]);
            dst[1] = pack2(acc[ai][bj][2], acc[ai][bj][3]);
        }
    }
}

// ---------------------------------------------------------------------------
// Kernel 2: fused flow sampling + multi-head attention, software-pipelined.
// 256 threads = 4 waves; 16 lanes/pixel (8 ch/lane), 16 pixels/block.
// grid = 1024. oh written IN-PLACE into the qp slab.
// ---------------------------------------------------------------------------

#define KVLOAD(BUF, BASE, R) { \
    const ushort16* r_ = (BASE) + roff[R]; \
    _Pragma("unroll") \
    for (int rx = 0; rx < 6; ++rx) \
        BUF[rx] = *reinterpret_cast<const uint4*>(r_ + coff[rx]); }

#define DOT8(U) \
    fmaf(qv[7], bf_hi((U).w), fmaf(qv[6], bf_lo((U).w), \
    fmaf(qv[5], bf_hi((U).z), fmaf(qv[4], bf_lo((U).z), \
    fmaf(qv[3], bf_hi((U).y), fmaf(qv[2], bf_lo((U).y), \
    fmaf(qv[1], bf_hi((U).x), qv[0] * bf_lo((U).x))))))))

#define KCONSUME(BUF, R) { \
    float pd_[6]; \
    _Pragma("unroll") \
    for (int rx = 0; rx < 6; ++rx) pd_[rx] = DOT8(BUF[rx]); \
    float hbr_[5]; \
    _Pragma("unroll") \
    for (int kx = 0; kx < 5; ++kx) \
        hbr_[kx] = pd_[kx] * XA[kx] + pd_[kx + 1] * XB[kx + 1]; \
    if ((R) < 5) { \
        _Pragma("unroll") \
        for (int kx = 0; kx < 5; ++kx) l[(R) * 5 + kx] = hbr_[kx] * YT[R]; } \
    if ((R) >= 1) { \
        _Pragma("unroll") \
        for (int kx = 0; kx < 5; ++kx) \
            l[((R) - 1) * 5 + kx] = fmaf(hbr_[kx], YB[R], l[((R) - 1) * 5 + kx]); } }

#define VCONSUME(BUF, R) { \
    float lhc_[6]; \
    if ((R) < 5) { \
        lhc_[0] = l[(R) * 5 + 0] * XA[0]; \
        _Pragma("unroll") \
        for (int rx = 1; rx < 5; ++rx) \
            lhc_[rx] = l[(R) * 5 + rx] * XA[rx] + l[(R) * 5 + rx - 1] * XB[rx]; \
        lhc_[5] = l[(R) * 5 + 4] * XB[5]; \
    } else { \
        _Pragma("unroll") \
        for (int rx = 0; rx < 6; ++rx) lhc_[rx] = 0.f; \
    } \
    _Pragma("unroll") \
    for (int rx = 0; rx < 6; ++rx) { \
        float w6_ = lhc_[rx] * YT[R] + lhp[rx] * YB[R]; \
        uint4 u_ = BUF[rx]; \
        acc[0] = fmaf(bf_lo(u_.x), w6_, acc[0]); \
        acc[1] = fmaf(bf_hi(u_.x), w6_, acc[1]); \
        acc[2] = fmaf(bf_lo(u_.y), w6_, acc[2]); \
        acc[3] = fmaf(bf_hi(u_.y), w6_, acc[3]); \
        acc[4] = fmaf(bf_lo(u_.z), w6_, acc[4]); \
        acc[5] = fmaf(bf_hi(u_.z), w6_, acc[5]); \
        acc[6] = fmaf(bf_lo(u_.w), w6_, acc[6]); \
        acc[7] = fmaf(bf_hi(u_.w), w6_, acc[7]); \
    } \
    _Pragma("unroll") \
    for (int rx = 0; rx < 6; ++rx) lhp[rx] = lhc_[rx]; }

__global__ __launch_bounds__(256) void attn_kernel(
    ushort16* qoh,
    const ushort16* __restrict__ kp, const ushort16* __restrict__ vp,
    const float* __restrict__ flow,
    float* __restrict__ attn)
{
    int blk = blockIdx.x;                        // 0..1023
    int swz = ((blk & 7) << 7) + (blk >> 3);     // XCD-contiguous bands
    int tid = threadIdx.x;
    int pix = swz * 16 + (tid >> 4);             // global pixel 0..16383
    int lg  = tid & 15;
    int c0  = lg * 8;
    int n   = pix >> 12;
    int yx  = pix & 4095;
    int y   = yx >> 6, x = yx & 63;

    float fx = flow[((size_t)n * 2 + 0) * HWp + yx];
    float fy = flow[((size_t)n * 2 + 1) * HWp + yx];
    float pxf = (float)x + fx, pyf = (float)y + fy;
    float X0 = floorf(pxf), Y0 = floorf(pyf);
    float wx = pxf - X0,    wy = pyf - Y0;
    int ix0 = (int)X0 - 2,  iy0 = (int)Y0 - 2;

    int coff[6], roff[6];
    float XA[6], XB[6], YT[6], YB[6];
#pragma unroll
    for (int r = 0; r < 6; ++r) {
        int xi = ix0 + r;
        float mx = (xi >= 0 && xi < WW) ? 1.f : 0.f;
        int xc = xi < 0 ? 0 : (xi > WW - 1 ? WW - 1 : xi);
        coff[r] = xc * CC;
        XA[r] = (1.f - wx) * mx;
        XB[r] = wx * mx;
        int yi = iy0 + r;
        float my = (yi >= 0 && yi < HH) ? 1.f : 0.f;
        int yc = yi < 0 ? 0 : (yi > HH - 1 ? HH - 1 : yi);
        roff[r] = yc * (WW * CC);
        YT[r] = (1.f - wy) * my;
        YB[r] = wy * my;
    }

    const ushort16* kb  = kp + (size_t)n * HWp * CC + c0;
    const ushort16* vbp = vp + (size_t)n * HWp * CC + c0;
    ushort16* qb = qoh + (size_t)pix * CC + c0;

    uint4 qraw = *reinterpret_cast<const uint4*>(qb);
    float qv[8] = { bf_lo(qraw.x), bf_hi(qraw.x), bf_lo(qraw.y), bf_hi(qraw.y),
                    bf_lo(qraw.z), bf_hi(qraw.z), bf_lo(qraw.w), bf_hi(qraw.w) };

    // ---- K pass: 2-buffer row pipeline ----
    float l[25];
    {
        uint4 kA[6], kB[6];
        KVLOAD(kA, kb, 0)
        KVLOAD(kB, kb, 1)
        KCONSUME(kA, 0)
        KVLOAD(kA, kb, 2)
        KCONSUME(kB, 1)
        KVLOAD(kB, kb, 3)
        KCONSUME(kA, 2)
        KVLOAD(kA, kb, 4)
        KCONSUME(kB, 3)
        KVLOAD(kB, kb, 5)
        KCONSUME(kA, 4)
        KCONSUME(kB, 5)
    }

    // ---- V prologue issued early: hides under reduce+softmax VALU ----
    uint4 vA[6], vB[6];
    KVLOAD(vA, vbp, 0)
    KVLOAD(vB, vbp, 1)

    // ---- reduce over 4 lanes (=32 ch) of this head ----
#pragma unroll
    for (int kk = 0; kk < 25; ++kk) {
        float s = l[kk];
        s += __shfl_xor(s, 1);
        s += __shfl_xor(s, 2);
        l[kk] = s * 0.17677669529663687f;   // 1/sqrt(32)
    }

    // ---- softmax over 25 ----
    float m = l[0];
#pragma unroll
    for (int kk = 1; kk < 25; ++kk) m = fmaxf(m, l[kk]);
    float sum = 0.f;
#pragma unroll
    for (int kk = 0; kk < 25; ++kk) { l[kk] = __expf(l[kk] - m); sum += l[kk]; }
    float inv = 1.f / sum;
#pragma unroll
    for (int kk = 0; kk < 25; ++kk) l[kk] *= inv;

    // ---- V pass: 2-buffer row pipeline ----
    float acc[8] = {0.f, 0.f, 0.f, 0.f, 0.f, 0.f, 0.f, 0.f};
    float lhp[6] = {0.f, 0.f, 0.f, 0.f, 0.f, 0.f};
    VCONSUME(vA, 0)
    KVLOAD(vA, vbp, 2)
    VCONSUME(vB, 1)
    KVLOAD(vB, vbp, 3)
    VCONSUME(vA, 2)
    KVLOAD(vA, vbp, 4)
    VCONSUME(vB, 3)
    KVLOAD(vB, vbp, 5)
    VCONSUME(vA, 4)
    VCONSUME(vB, 5)

    // ---- stores last: attn (fp32, reference layout) then oh in-place ----
    {
        int head = lg >> 2, j = lg & 3;
        float* ab = attn + (((size_t)n * NHEADS + head) * K2) * HWp + yx;
#pragma unroll
        for (int kk = 0; kk < 25; ++kk)
            if ((kk & 3) == j) ab[(size_t)kk * HWp] = l[kk];
    }

    uint4 o;
    o.x = pack2(acc[0], acc[1]);
    o.y = pack2(acc[2], acc[3]);
    o.z = pack2(acc[4], acc[5]);
    o.w = pack2(acc[6], acc[7]);
    *reinterpret_cast<uint4*>(qb) = o;     // oh, in-place over qp
}

// ---------------------------------------------------------------------------
// Kernel 3: MFMA final projection. out[o][pix] = Wfc * oh[pix][c]^T.
// ---------------------------------------------------------------------------
__global__ __launch_bounds__(256) void fc_mfma(
    const ushort16* __restrict__ oh, const ushort16* __restrict__ wfcb,
    float* __restrict__ out)
{
    int blk = blockIdx.x;
    int gp0 = blk * 64;
    int n   = gp0 >> 12;
    int yx0 = gp0 & 4095;

    int lane = threadIdx.x & 63;
    int wid  = threadIdx.x >> 6;
    int wr = wid >> 1, wc = wid & 1;
    int p16 = lane & 15, kg = lane >> 4;

    const ushort16* ohb = oh + (size_t)gp0 * CC;

    f32x4 acc[4][2] = {};

#pragma unroll
    for (int k0 = 0; k0 < 128; k0 += 32) {
        bf16x8 A[4], B[2];
#pragma unroll
        for (int ai = 0; ai < 4; ++ai) {
            int o = wr * 64 + ai * 16 + p16;
            A[ai] = *reinterpret_cast<const bf16x8*>(&wfcb[o * 128 + k0 + kg * 8]);
        }
#pragma unroll
        for (int bj = 0; bj < 2; ++bj) {
            int px = wc * 32 + bj * 16 + p16;
            B[bj] = *reinterpret_cast<const bf16x8*>(&ohb[(size_t)px * CC + k0 + kg * 8]);
        }
#pragma unroll
        for (int ai = 0; ai < 4; ++ai)
#pragma unroll
            for (int bj = 0; bj < 2; ++bj)
                acc[ai][bj] = __builtin_amdgcn_mfma_f32_16x16x32_bf16(
                    A[ai], B[bj], acc[ai][bj], 0, 0, 0);
    }

    float* ob = out + (size_t)n * CC * HWp + yx0;
#pragma unroll
    for (int ai = 0; ai < 4; ++ai) {
        int o = wr * 64 + ai * 16 + kg * 4;
#pragma unroll
        for (int bj = 0; bj < 2; ++bj) {
            int px = wc * 32 + bj * 16 + p16;
#pragma unroll
            for (int r = 0; r < 4; ++r)
                ob[(size_t)(o + r) * HWp + px] = acc[ai][bj][r];
        }
    }
}

// ---------------------------------------------------------------------------
extern "C" void kernel_launch(void* const* d_in, const int* in_sizes, int n_in,
                              void* d_out, int out_size, void* d_ws, size_t ws_size,
                              hipStream_t stream)
{
    const float* q    = (const float*)d_in[0];
    const float* k    = (const float*)d_in[1];
    const float* v    = (const float*)d_in[2];
    const float* flow = (const float*)d_in[3];
    const float* Wq   = (const float*)d_in[4];
    const float* Wk   = (const float*)d_in[5];
    const float* Wv   = (const float*)d_in[6];
    const float* Wfc  = (const float*)d_in[7];

    float* out  = (float*)d_out;                          // [N][C][H][W]
    float* attn = out + (size_t)NB * CC * HWp;            // [N][NHEADS][K2][H][W]

    ushort16* ws = (ushort16*)d_ws;
    size_t slab = (size_t)NB * HWp * CC;
    ushort16* qp  = ws;                                   // q -> oh in-place
    ushort16* kp  = ws + slab;
    ushort16* vp  = ws + 2 * slab;
    ushort16* wbf = ws + 3 * slab;

    wconv_kernel<<<dim3(64), dim3(256), 0, stream>>>(Wq, Wk, Wv, Wfc, wbf);
    proj_mfma<<<dim3(768), dim3(256), 0, stream>>>(q, k, v, wbf, qp, kp, vp);
    attn_kernel<<<dim3(1024), dim3(256), 0, stream>>>(qp, kp, vp, flow, attn);
    fc_mfma<<<dim3(256), dim3(256), 0, stream>>>(qp, wbf + 3 * 16384, out);
}

// Round 7
// 50.400 us; speedup vs baseline: 3.1576x; 1.0067x over previous
//
#include <hip/hip_runtime.h>

constexpr int NB = 4;
constexpr int CC = 128;
constexpr int HH = 64;
constexpr int WW = 64;
constexpr int HWp = HH * WW;      // 4096
constexpr int NHEADS = 4;
constexpr int K2 = 25;

typedef unsigned int   uint32;
typedef unsigned short ushort16;
typedef __attribute__((ext_vector_type(8))) short bf16x8;
typedef __attribute__((ext_vector_type(4))) float f32x4;

__device__ __forceinline__ ushort16 f2bf(float x) {
    uint32 b = __float_as_uint(x);
    return (ushort16)((b + 0x7FFFu + ((b >> 16) & 1u)) >> 16);   // RNE
}
__device__ __forceinline__ uint32 pack2(float lo, float hi) {
    return ((uint32)f2bf(hi) << 16) | (uint32)f2bf(lo);
}
__device__ __forceinline__ float bf_lo(uint32 u) { return __uint_as_float(u << 16); }
__device__ __forceinline__ float bf_hi(uint32 u) { return __uint_as_float(u & 0xFFFF0000u); }

// ---------------------------------------------------------------------------
// Kernel 0: convert Wq/Wk/Wv/Wfc fp32 -> bf16 (row-major preserved).
// ---------------------------------------------------------------------------
__global__ __launch_bounds__(256) void wconv_kernel(
    const float* __restrict__ Wq, const float* __restrict__ Wk,
    const float* __restrict__ Wv, const float* __restrict__ Wfc,
    ushort16* __restrict__ wbf)
{
    int i = blockIdx.x * 256 + threadIdx.x;   // 0..16383
    int m = i >> 12;
    int j = i & 4095;
    const float* s = (m == 0) ? Wq : ((m == 1) ? Wk : ((m == 2) ? Wv : Wfc));
    float4 f = reinterpret_cast<const float4*>(s)[j];
    uint32 w0 = pack2(f.x, f.y);
    uint32 w1 = pack2(f.z, f.w);
    uint32* d = reinterpret_cast<uint32*>(wbf + (size_t)m * 16384);
    d[j * 2]     = w0;
    d[j * 2 + 1] = w1;
}

// ---------------------------------------------------------------------------
// Kernel 1: MFMA projections. C[out=128][pix] = W[128x128] * X[c=128][pix].
// grid = 3 * NB * 64 = 768 blocks, 256 threads (2x2 wave grid).
// ---------------------------------------------------------------------------
__global__ __launch_bounds__(256) void proj_mfma(
    const float* __restrict__ q, const float* __restrict__ k, const float* __restrict__ v,
    const ushort16* __restrict__ wbf,
    ushort16* __restrict__ qp, ushort16* __restrict__ kp, ushort16* __restrict__ vp)
{
    __shared__ __align__(16) ushort16 lx[64 * 132];

    int blk = blockIdx.x;
    int p   = blk >> 8;
    int rem = blk & 255;
    int n   = rem >> 6;
    int pt  = rem & 63;
    int pix0 = pt * 64;

    const float*    X  = (p == 0) ? q  : ((p == 1) ? k  : v);
    ushort16*       O  = (p == 0) ? qp : ((p == 1) ? kp : vp);
    const ushort16* Wb = wbf + (size_t)p * 16384;
    const float*    Xb = X + (size_t)n * CC * HWp + pix0;

    int lane = threadIdx.x & 63;
    int cg   = threadIdx.x >> 6;

#pragma unroll
    for (int i = 0; i < 16; ++i) {
        int c0 = i * 8 + cg * 2;
        float a = Xb[c0 * HWp + lane];
        float b = Xb[(c0 + 1) * HWp + lane];
        *reinterpret_cast<uint32*>(&lx[lane * 132 + c0]) = pack2(a, b);
    }
    __syncthreads();

    int wid = threadIdx.x >> 6;
    int wr  = wid >> 1, wc = wid & 1;
    int p16 = lane & 15, kg = lane >> 4;

    f32x4 acc[4][2] = {};

#pragma unroll
    for (int k0 = 0; k0 < 128; k0 += 32) {
        bf16x8 A[4], B[2];
#pragma unroll
        for (int ai = 0; ai < 4; ++ai) {
            int o = wr * 64 + ai * 16 + p16;
            A[ai] = *reinterpret_cast<const bf16x8*>(&Wb[o * 128 + k0 + kg * 8]);
        }
#pragma unroll
        for (int bj = 0; bj < 2; ++bj) {
            int px = wc * 32 + bj * 16 + p16;
            const ushort16* sp = &lx[px * 132 + k0 + kg * 8];
            struct { unsigned long long lo, hi; } t;
            t.lo = *reinterpret_cast<const unsigned long long*>(sp);
            t.hi = *reinterpret_cast<const unsigned long long*>(sp + 4);
            B[bj] = __builtin_bit_cast(bf16x8, t);
        }
#pragma unroll
        for (int ai = 0; ai < 4; ++ai)
#pragma unroll
            for (int bj = 0; bj < 2; ++bj)
                acc[ai][bj] = __builtin_amdgcn_mfma_f32_16x16x32_bf16(
                    A[ai], B[bj], acc[ai][bj], 0, 0, 0);
    }

    ushort16* Ob = O + (size_t)(n * HWp + pix0) * CC;
#pragma unroll
    for (int ai = 0; ai < 4; ++ai) {
        int ob = wr * 64 + ai * 16 + kg * 4;
#pragma unroll
        for (int bj = 0; bj < 2; ++bj) {
            int px = wc * 32 + bj * 16 + p16;
            uint32* dst = reinterpret_cast<uint32*>(&Ob[(size_t)px * CC + ob]);
            dst[0] = pack2(acc[ai][bj][0], acc[ai][bj][1]);
            dst[1] = pack2(acc[ai][bj][2], acc[ai][bj][3]);
        }
    }
}

// ---------------------------------------------------------------------------
// Kernel 2: fused flow sampling + multi-head attention, software-pipelined.
// 64-thread blocks (1 wave = 4 pixels), grid 4096: block turnover staggers
// wave phases per SIMD so gather latency overlaps across waves.
// oh written IN-PLACE into the qp slab.
// ---------------------------------------------------------------------------

#define KVLOAD(BUF, BASE, R) { \
    const ushort16* r_ = (BASE) + roff[R]; \
    _Pragma("unroll") \
    for (int rx = 0; rx < 6; ++rx) \
        BUF[rx] = *reinterpret_cast<const uint4*>(r_ + coff[rx]); }

#define DOT8(U) \
    fmaf(qv[7], bf_hi((U).w), fmaf(qv[6], bf_lo((U).w), \
    fmaf(qv[5], bf_hi((U).z), fmaf(qv[4], bf_lo((U).z), \
    fmaf(qv[3], bf_hi((U).y), fmaf(qv[2], bf_lo((U).y), \
    fmaf(qv[1], bf_hi((U).x), qv[0] * bf_lo((U).x))))))))

#define KCONSUME(BUF, R) { \
    float pd_[6]; \
    _Pragma("unroll") \
    for (int rx = 0; rx < 6; ++rx) pd_[rx] = DOT8(BUF[rx]); \
    float hbr_[5]; \
    _Pragma("unroll") \
    for (int kx = 0; kx < 5; ++kx) \
        hbr_[kx] = pd_[kx] * XA[kx] + pd_[kx + 1] * XB[kx + 1]; \
    if ((R) < 5) { \
        _Pragma("unroll") \
        for (int kx = 0; kx < 5; ++kx) l[(R) * 5 + kx] = hbr_[kx] * YT[R]; } \
    if ((R) >= 1) { \
        _Pragma("unroll") \
        for (int kx = 0; kx < 5; ++kx) \
            l[((R) - 1) * 5 + kx] = fmaf(hbr_[kx], YB[R], l[((R) - 1) * 5 + kx]); } }

#define VCONSUME(BUF, R) { \
    float lhc_[6]; \
    if ((R) < 5) { \
        lhc_[0] = l[(R) * 5 + 0] * XA[0]; \
        _Pragma("unroll") \
        for (int rx = 1; rx < 5; ++rx) \
            lhc_[rx] = l[(R) * 5 + rx] * XA[rx] + l[(R) * 5 + rx - 1] * XB[rx]; \
        lhc_[5] = l[(R) * 5 + 4] * XB[5]; \
    } else { \
        _Pragma("unroll") \
        for (int rx = 0; rx < 6; ++rx) lhc_[rx] = 0.f; \
    } \
    _Pragma("unroll") \
    for (int rx = 0; rx < 6; ++rx) { \
        float w6_ = lhc_[rx] * YT[R] + lhp[rx] * YB[R]; \
        uint4 u_ = BUF[rx]; \
        acc[0] = fmaf(bf_lo(u_.x), w6_, acc[0]); \
        acc[1] = fmaf(bf_hi(u_.x), w6_, acc[1]); \
        acc[2] = fmaf(bf_lo(u_.y), w6_, acc[2]); \
        acc[3] = fmaf(bf_hi(u_.y), w6_, acc[3]); \
        acc[4] = fmaf(bf_lo(u_.z), w6_, acc[4]); \
        acc[5] = fmaf(bf_hi(u_.z), w6_, acc[5]); \
        acc[6] = fmaf(bf_lo(u_.w), w6_, acc[6]); \
        acc[7] = fmaf(bf_hi(u_.w), w6_, acc[7]); \
    } \
    _Pragma("unroll") \
    for (int rx = 0; rx < 6; ++rx) lhp[rx] = lhc_[rx]; }

__global__ __launch_bounds__(64) void attn_kernel(
    ushort16* qoh,
    const ushort16* __restrict__ kp, const ushort16* __restrict__ vp,
    const float* __restrict__ flow,
    float* __restrict__ attn)
{
    int blk = blockIdx.x;                        // 0..4095
    int swz = ((blk & 7) << 9) + (blk >> 3);     // XCD-contiguous pixel bands
    int tid = threadIdx.x;                       // 0..63
    int pix = swz * 4 + (tid >> 4);              // global pixel 0..16383
    int lg  = tid & 15;
    int c0  = lg * 8;
    int n   = pix >> 12;
    int yx  = pix & 4095;
    int y   = yx >> 6, x = yx & 63;

    float fx = flow[((size_t)n * 2 + 0) * HWp + yx];
    float fy = flow[((size_t)n * 2 + 1) * HWp + yx];
    float pxf = (float)x + fx, pyf = (float)y + fy;
    float X0 = floorf(pxf), Y0 = floorf(pyf);
    float wx = pxf - X0,    wy = pyf - Y0;
    int ix0 = (int)X0 - 2,  iy0 = (int)Y0 - 2;

    int coff[6], roff[6];
    float XA[6], XB[6], YT[6], YB[6];
#pragma unroll
    for (int r = 0; r < 6; ++r) {
        int xi = ix0 + r;
        float mx = (xi >= 0 && xi < WW) ? 1.f : 0.f;
        int xc = xi < 0 ? 0 : (xi > WW - 1 ? WW - 1 : xi);
        coff[r] = xc * CC;
        XA[r] = (1.f - wx) * mx;
        XB[r] = wx * mx;
        int yi = iy0 + r;
        float my = (yi >= 0 && yi < HH) ? 1.f : 0.f;
        int yc = yi < 0 ? 0 : (yi > HH - 1 ? HH - 1 : yi);
        roff[r] = yc * (WW * CC);
        YT[r] = (1.f - wy) * my;
        YB[r] = wy * my;
    }

    const ushort16* kb  = kp + (size_t)n * HWp * CC + c0;
    const ushort16* vbp = vp + (size_t)n * HWp * CC + c0;
    ushort16* qb = qoh + (size_t)pix * CC + c0;

    uint4 qraw = *reinterpret_cast<const uint4*>(qb);
    float qv[8] = { bf_lo(qraw.x), bf_hi(qraw.x), bf_lo(qraw.y), bf_hi(qraw.y),
                    bf_lo(qraw.z), bf_hi(qraw.z), bf_lo(qraw.w), bf_hi(qraw.w) };

    // ---- K pass: 2-buffer row pipeline ----
    float l[25];
    {
        uint4 kA[6], kB[6];
        KVLOAD(kA, kb, 0)
        KVLOAD(kB, kb, 1)
        KCONSUME(kA, 0)
        KVLOAD(kA, kb, 2)
        KCONSUME(kB, 1)
        KVLOAD(kB, kb, 3)
        KCONSUME(kA, 2)
        KVLOAD(kA, kb, 4)
        KCONSUME(kB, 3)
        KVLOAD(kB, kb, 5)
        KCONSUME(kA, 4)
        KCONSUME(kB, 5)
    }

    // ---- V prologue issued early: hides under reduce+softmax VALU ----
    uint4 vA[6], vB[6];
    KVLOAD(vA, vbp, 0)
    KVLOAD(vB, vbp, 1)

    // ---- reduce over 4 lanes (=32 ch) of this head ----
#pragma unroll
    for (int kk = 0; kk < 25; ++kk) {
        float s = l[kk];
        s += __shfl_xor(s, 1);
        s += __shfl_xor(s, 2);
        l[kk] = s * 0.17677669529663687f;   // 1/sqrt(32)
    }

    // ---- softmax over 25 ----
    float m = l[0];
#pragma unroll
    for (int kk = 1; kk < 25; ++kk) m = fmaxf(m, l[kk]);
    float sum = 0.f;
#pragma unroll
    for (int kk = 0; kk < 25; ++kk) { l[kk] = __expf(l[kk] - m); sum += l[kk]; }
    float inv = 1.f / sum;
#pragma unroll
    for (int kk = 0; kk < 25; ++kk) l[kk] *= inv;

    // ---- V pass: 2-buffer row pipeline ----
    float acc[8] = {0.f, 0.f, 0.f, 0.f, 0.f, 0.f, 0.f, 0.f};
    float lhp[6] = {0.f, 0.f, 0.f, 0.f, 0.f, 0.f};
    VCONSUME(vA, 0)
    KVLOAD(vA, vbp, 2)
    VCONSUME(vB, 1)
    KVLOAD(vB, vbp, 3)
    VCONSUME(vA, 2)
    KVLOAD(vA, vbp, 4)
    VCONSUME(vB, 3)
    KVLOAD(vB, vbp, 5)
    VCONSUME(vA, 4)
    VCONSUME(vB, 5)

    // ---- stores last: attn (fp32, reference layout) then oh in-place ----
    {
        int head = lg >> 2, j = lg & 3;
        float* ab = attn + (((size_t)n * NHEADS + head) * K2) * HWp + yx;
#pragma unroll
        for (int kk = 0; kk < 25; ++kk)
            if ((kk & 3) == j) ab[(size_t)kk * HWp] = l[kk];
    }

    uint4 o;
    o.x = pack2(acc[0], acc[1]);
    o.y = pack2(acc[2], acc[3]);
    o.z = pack2(acc[4], acc[5]);
    o.w = pack2(acc[6], acc[7]);
    *reinterpret_cast<uint4*>(qb) = o;     // oh, in-place over qp
}

// ---------------------------------------------------------------------------
// Kernel 3: MFMA final projection. out[o][pix] = Wfc * oh[pix][c]^T.
// ---------------------------------------------------------------------------
__global__ __launch_bounds__(256) void fc_mfma(
    const ushort16* __restrict__ oh, const ushort16* __restrict__ wfcb,
    float* __restrict__ out)
{
    int blk = blockIdx.x;
    int gp0 = blk * 64;
    int n   = gp0 >> 12;
    int yx0 = gp0 & 4095;

    int lane = threadIdx.x & 63;
    int wid  = threadIdx.x >> 6;
    int wr = wid >> 1, wc = wid & 1;
    int p16 = lane & 15, kg = lane >> 4;

    const ushort16* ohb = oh + (size_t)gp0 * CC;

    f32x4 acc[4][2] = {};

#pragma unroll
    for (int k0 = 0; k0 < 128; k0 += 32) {
        bf16x8 A[4], B[2];
#pragma unroll
        for (int ai = 0; ai < 4; ++ai) {
            int o = wr * 64 + ai * 16 + p16;
            A[ai] = *reinterpret_cast<const bf16x8*>(&wfcb[o * 128 + k0 + kg * 8]);
        }
#pragma unroll
        for (int bj = 0; bj < 2; ++bj) {
            int px = wc * 32 + bj * 16 + p16;
            B[bj] = *reinterpret_cast<const bf16x8*>(&ohb[(size_t)px * CC + k0 + kg * 8]);
        }
#pragma unroll
        for (int ai = 0; ai < 4; ++ai)
#pragma unroll
            for (int bj = 0; bj < 2; ++bj)
                acc[ai][bj] = __builtin_amdgcn_mfma_f32_16x16x32_bf16(
                    A[ai], B[bj], acc[ai][bj], 0, 0, 0);
    }

    float* ob = out + (size_t)n * CC * HWp + yx0;
#pragma unroll
    for (int ai = 0; ai < 4; ++ai) {
        int o = wr * 64 + ai * 16 + kg * 4;
#pragma unroll
        for (int bj = 0; bj < 2; ++bj) {
            int px = wc * 32 + bj * 16 + p16;
#pragma unroll
            for (int r = 0; r < 4; ++r)
                ob[(size_t)(o + r) * HWp + px] = acc[ai][bj][r];
        }
    }
}

// ---------------------------------------------------------------------------
extern "C" void kernel_launch(void* const* d_in, const int* in_sizes, int n_in,
                              void* d_out, int out_size, void* d_ws, size_t ws_size,
                              hipStream_t stream)
{
    const float* q    = (const float*)d_in[0];
    const float* k    = (const float*)d_in[1];
    const float* v    = (const float*)d_in[2];
    const float* flow = (const float*)d_in[3];
    const float* Wq   = (const float*)d_in[4];
    const float* Wk   = (const float*)d_in[5];
    const float* Wv   = (const float*)d_in[6];
    const float* Wfc  = (const float*)d_in[7];

    float* out  = (float*)d_out;                          // [N][C][H][W]
    float* attn = out + (size_t)NB * CC * HWp;            // [N][NHEADS][K2][H][W]

    ushort16* ws = (ushort16*)d_ws;
    size_t slab = (size_t)NB * HWp * CC;
    ushort16* qp  = ws;                                   // q -> oh in-place
    ushort16* kp  = ws + slab;
    ushort16* vp  = ws + 2 * slab;
    ushort16* wbf = ws + 3 * slab;

    wconv_kernel<<<dim3(64), dim3(256), 0, stream>>>(Wq, Wk, Wv, Wfc, wbf);
    proj_mfma<<<dim3(768), dim3(256), 0, stream>>>(q, k, v, wbf, qp, kp, vp);
    attn_kernel<<<dim3(4096), dim3(64), 0, stream>>>(qp, kp, vp, flow, attn);
    fc_mfma<<<dim3(256), dim3(256), 0, stream>>>(qp, wbf + 3 * 16384, out);
}